// Round 8
// baseline (819.858 us; speedup 1.0000x reference)
//
#include <hip/hip_runtime.h>
#include <hip/hip_bf16.h>
#include <type_traits>

#define B_   2
#define L_   1024
#define DM   512
#define DI   1024
#define DS   16
#define DTR  32
#define ROWS (B_*L_)
#define NCH  16            // number of scan chunks
#define CHUNK (L_/NCH)     // 64 steps per chunk
#define HC   32            // half-chunk staged at a time

// param-pool element offsets (bf16 pool holding all small/medium weights)
#define PO_CW    0
#define PO_CB    32768
#define PO_XPW   40960
#define PO_DTW   565248
#define PO_DTB   827392
#define PO_ALOG  835584
#define PO_DP    966656
#define PO_LNW   974848
#define PO_LNB   976896
#define PO_FNW   978944
#define PO_FNB   979456
#define PO_END   979968

#define N_WIN    (4*2097152)
#define N_WOUT   (4*1048576)
#define N_X      1048576

typedef __bf16 bf16x8 __attribute__((ext_vector_type(8)));
typedef float  f32x4  __attribute__((ext_vector_type(4)));
using bf16 = __hip_bfloat16;

__device__ __forceinline__ bf16x8 ld8(const bf16* p){
    return *reinterpret_cast<const bf16x8*>(p);
}
__device__ __forceinline__ float b2f(bf16 v){ return __bfloat162float(v); }

__device__ __forceinline__ unsigned pkbf2(float a, float b){
    bf16 ha = __float2bfloat16(a), hb = __float2bfloat16(b);
    unsigned short ua = *(unsigned short*)&ha, ub = *(unsigned short*)&hb;
    return (unsigned)ua | ((unsigned)ub << 16);
}
__device__ __forceinline__ float unpk_lo(unsigned v){
    unsigned x = v << 16; return __builtin_bit_cast(float, x);
}
__device__ __forceinline__ float unpk_hi(unsigned v){
    unsigned x = v & 0xffff0000u; return __builtin_bit_cast(float, x);
}

__device__ __forceinline__ void async_cp16(const bf16* g, bf16* s){
    __builtin_amdgcn_global_load_lds(
        (const __attribute__((address_space(1))) unsigned int*)g,
        (__attribute__((address_space(3))) unsigned int*)s, 16, 0, 0);
}

// ---------------------------------------------------------------- dtype detect
__global__ void detect_kernel(const void* Dp_raw, int* flag){
    *flag = (*(const unsigned int*)Dp_raw == 0x3F800000u) ? 1 : 0;
}

__device__ __forceinline__ bf16 cvload(const void* s, long o, int f){
    return f ? __float2bfloat16(((const float*)s)[o]) : ((const bf16*)s)[o];
}

// ---------------------------------------------------------------- mega convert
__global__ void megacvt_kernel(const void* cw, const void* cb, const void* xpw,
                               const void* dtw, const void* dtb, const void* al,
                               const void* dp, const void* lnw, const void* lnb,
                               const void* fnw, const void* fnb,
                               const void* inw, const void* outw, const void* xin,
                               bf16* PP, bf16* WIN, bf16* WOUT,
                               float* X, float* R, const int* flag){
    long i = (long)blockIdx.x*256 + threadIdx.x;
    int f = *flag;
    if (i < PO_END){
        const void* s; long o;
        if      (i < PO_CB)   { s = cw;  o = i; }
        else if (i < PO_XPW)  { s = cb;  o = i - PO_CB; }
        else if (i < PO_DTW)  { s = xpw; o = i - PO_XPW; }
        else if (i < PO_DTB)  { s = dtw; o = i - PO_DTW; }
        else if (i < PO_ALOG) { s = dtb; o = i - PO_DTB; }
        else if (i < PO_DP)   { s = al;  o = i - PO_ALOG; }
        else if (i < PO_LNW)  { s = dp;  o = i - PO_DP; }
        else if (i < PO_LNB)  { s = lnw; o = i - PO_LNW; }
        else if (i < PO_FNW)  { s = lnb; o = i - PO_LNB; }
        else if (i < PO_FNB)  { s = fnw; o = i - PO_FNW; }
        else                  { s = fnb; o = i - PO_FNB; }
        PP[i] = cvload(s, o, f);
        return;
    }
    i -= PO_END;
    if (i < N_WIN){ WIN[i] = cvload(inw, i, f); return; }
    i -= N_WIN;
    if (i < N_WOUT){
        long l = i >> 20, r = i & 1048575;
        long n = r >> 11, dir = (r >> 10) & 1, d = r & 1023;
        WOUT[i] = cvload(outw, ((l*2 + dir)*512 + n)*1024 + d, f);
        return;
    }
    i -= N_WOUT;
    if (i < N_X){
        X[i] = f ? ((const float*)xin)[i] : b2f(((const bf16*)xin)[i]);
        R[i] = 0.f;
    }
}

// ---------------------------------------------------------------- layernorm
__global__ void ln_kernel(const float* __restrict__ P, int nparts,
                          float* __restrict__ R,
                          const bf16* __restrict__ w, const bf16* __restrict__ b,
                          void* __restrict__ out, int mode, const int* flag){
    int row = blockIdx.x, lane = threadIdx.x;   // block = 64 (one wave)
    size_t base = (size_t)row*DM + lane*8;
    float v[8];
    *(float4*)&v[0] = *(const float4*)(P+base);
    *(float4*)&v[4] = *(const float4*)(P+base+4);
    for (int k=1; k<nparts; ++k){
        float4 a0 = *(const float4*)(P + (size_t)k*1048576 + base);
        float4 a1 = *(const float4*)(P + (size_t)k*1048576 + base + 4);
        v[0]+=a0.x; v[1]+=a0.y; v[2]+=a0.z; v[3]+=a0.w;
        v[4]+=a1.x; v[5]+=a1.y; v[6]+=a1.z; v[7]+=a1.w;
    }
    if (mode == 0){
        float4 r0 = *(const float4*)(R+base);
        float4 r1 = *(const float4*)(R+base+4);
        r0.x += v[0]; r0.y += v[1]; r0.z += v[2]; r0.w += v[3];
        r1.x += v[4]; r1.y += v[5]; r1.z += v[6]; r1.w += v[7];
        *(float4*)(R+base)   = r0;
        *(float4*)(R+base+4) = r1;
    } else {
        float4 r0 = *(const float4*)(R+base);
        float4 r1 = *(const float4*)(R+base+4);
        v[0]+=r0.x; v[1]+=r0.y; v[2]+=r0.z; v[3]+=r0.w;
        v[4]+=r1.x; v[5]+=r1.y; v[6]+=r1.z; v[7]+=r1.w;
    }
    float s=0.f, sq=0.f;
    #pragma unroll
    for (int j=0;j<8;++j){ s += v[j]; sq += v[j]*v[j]; }
    #pragma unroll
    for (int off=32; off>=1; off>>=1){
        s  += __shfl_xor(s,  off, 64);
        sq += __shfl_xor(sq, off, 64);
    }
    float mean = s*(1.f/DM);
    float var  = sq*(1.f/DM) - mean*mean;
    float rs   = rsqrtf(var + 1e-5f);
    bf16x8 wv = ld8(w + lane*8), bv = ld8(b + lane*8);
    float res[8];
    #pragma unroll
    for (int j=0;j<8;++j)
        res[j] = (v[j]-mean)*rs*(float)wv[j] + (float)bv[j];
    if (mode == 1 && *flag){
        float* of = (float*)out;
        *(float4*)(of+base)   = make_float4(res[0],res[1],res[2],res[3]);
        *(float4*)(of+base+4) = make_float4(res[4],res[5],res[6],res[7]);
    } else {
        union { bf16 h[8]; uint4 u; } o;
        #pragma unroll
        for (int j=0;j<8;++j) o.h[j] = __float2bfloat16(res[j]);
        *(uint4*)((bf16*)out + base) = o.u;
    }
}

// ---------------------------------------------------------------- LDS-staged GEMM
template<int WM, int WN, int SK, typename CT>
__global__ __launch_bounds__(WM*WN*64)
void gemm_lds(const bf16* __restrict__ A, const bf16* __restrict__ W,
              CT* __restrict__ C, int K, int lda, int ldw, int ldc,
              int selTiles, long wSel){
    constexpr int BM = WM*64, BN = WN*64, T = WM*WN*64;
    constexpr int RA = (BM*4)/T, RB = (BN*4)/T;
    __shared__ __align__(16) bf16 sA[BM*32];
    __shared__ __align__(16) bf16 sB[BN*32];
    int tid = threadIdx.x;
    int mtile = blockIdx.y, ntile = blockIdx.x;
    if (mtile >= selTiles) W += wSel;
    int m0 = mtile*BM, n0 = ntile*BN;
    int kPer = K/SK, kBeg = blockIdx.z*kPer, kEnd = kBeg + kPer;
    if (SK > 1)
        C += (size_t)blockIdx.z * (size_t)(gridDim.y*BM) * (size_t)(gridDim.x*BN);
    int wave = tid>>6, lane = tid&63, quad = lane>>4, r = lane&15;
    int wrow = wave / WN, wcol = wave % WN;
    const bf16* Abase = A + (size_t)m0*lda;
    const bf16* Wbase = W + (size_t)n0*ldw;
    f32x4 acc[4][4] = {};
    for (int k0 = kBeg; k0 < kEnd; k0 += 32){
        #pragma unroll
        for (int rr=0; rr<RA; ++rr){
            int q = rr*T + tid;
            async_cp16(Abase + (size_t)(q>>2)*lda + k0 + (q&3)*8, &sA[q*8]);
        }
        #pragma unroll
        for (int rr=0; rr<RB; ++rr){
            int q = rr*T + tid;
            async_cp16(Wbase + (size_t)(q>>2)*ldw + k0 + (q&3)*8, &sB[q*8]);
        }
        __syncthreads();
        bf16x8 af[4], bw[4];
        #pragma unroll
        for (int mt=0; mt<4; ++mt)
            af[mt] = *(const bf16x8*)&sA[(wrow*64 + mt*16 + r)*32 + quad*8];
        #pragma unroll
        for (int nt=0; nt<4; ++nt)
            bw[nt] = *(const bf16x8*)&sB[(wcol*64 + nt*16 + r)*32 + quad*8];
        #pragma unroll
        for (int mt=0; mt<4; ++mt)
            #pragma unroll
            for (int nt=0; nt<4; ++nt)
                acc[mt][nt] = __builtin_amdgcn_mfma_f32_16x16x32_bf16(
                    af[mt], bw[nt], acc[mt][nt], 0,0,0);
        __syncthreads();
    }
    #pragma unroll
    for (int mt=0; mt<4; ++mt){
        #pragma unroll
        for (int nt=0; nt<4; ++nt){
            int col = n0 + wcol*64 + nt*16 + r;
            #pragma unroll
            for (int ri=0; ri<4; ++ri){
                int row = m0 + wrow*64 + mt*16 + quad*4 + ri;
                size_t idx = (size_t)row*ldc + col;
                if constexpr (std::is_same<CT, bf16>::value)
                    C[idx] = __float2bfloat16(acc[mt][nt][ri]);
                else
                    C[idx] = acc[mt][nt][ri];
            }
        }
    }
}

// reduce 8 x_proj partials [8][4096*64] -> XD[row][dir*64+j]
__global__ void reduce_xd(const float* __restrict__ P, float* __restrict__ XD){
    int i = blockIdx.x*256 + threadIdx.x;    // 262144
    float s = 0.f;
    #pragma unroll
    for (int k=0;k<8;++k) s += P[k*262144 + i];
    int j = i & 63, grow = i >> 6, dir = grow >> 11, row = grow & 2047;
    XD[row*128 + dir*64 + j] = s;
}

// ---------------------------------------------------------------- causal depthwise conv (k=4) + silu
__global__ void conv_kernel(const bf16* __restrict__ XZ, const bf16* __restrict__ cw,
                            const bf16* __restrict__ cb, bf16* __restrict__ XC){
    int id  = blockIdx.x*256 + threadIdx.x;
    int d   = id & (DI-1);
    int t   = (id >> 10) & (L_-1);
    int b   = (id >> 20) & 1;
    int dir = id >> 21;
    float wv[4];
    #pragma unroll
    for (int k=0;k<4;++k) wv[k] = b2f(cw[((size_t)dir*DI + d)*4 + k]);
    float acc = b2f(cb[dir*DI + d]);
    #pragma unroll
    for (int k=0;k<4;++k){
        int tau = t - 3 + k;
        if (tau >= 0){
            int sig = dir ? (L_-1-tau) : tau;
            acc += wv[k] * b2f(XZ[((size_t)(b*L_ + sig))*4096 + dir*2048 + d]);
        }
    }
    float s = acc * (1.f/(1.f + __expf(-acc)));
    XC[((size_t)dir*ROWS + (size_t)b*L_ + t)*DI + d] = __float2bfloat16(s);
}

// ---------------------------------------------------------------- dt projection + softplus + pack (dt, dt*u)
__global__ void dtproj_kernel(const float* __restrict__ XD, const bf16* __restrict__ dtw,
                              const bf16* __restrict__ dtb, const bf16* __restrict__ XC,
                              unsigned* __restrict__ DTW){
    int id  = blockIdx.x*256 + threadIdx.x;
    int d   = id & (DI-1);
    int row = (id >> 10) & (ROWS-1);
    int dir = id >> 21;
    const float* xr = XD + (size_t)row*128 + dir*64;
    const bf16*  wp = dtw + ((size_t)dir*DI + d)*DTR;
    float acc = b2f(dtb[dir*DI + d]);
    #pragma unroll
    for (int kk=0;kk<4;++kk){
        bf16x8 wv = ld8(wp + kk*8);
        #pragma unroll
        for (int j=0;j<8;++j) acc += xr[kk*8+j]*(float)wv[j];
    }
    float sp = acc > 20.f ? acc : log1pf(__expf(acc));
    size_t idx = ((size_t)dir*ROWS + row)*DI + d;
    float u = b2f(XC[idx]);
    DTW[idx] = pkbf2(sp, sp*u);
}

// ---------------------------------------------------------------- selective scan v5
// thread = (d, n-half): 8 states in registers; block = 128 d x 2 halves (256 thr)
// grid (8, NCH, 4dirb) = 512 blocks. Half-chunk (32-step) LDS staging of packed
// (dt, dt*u); y cross-half sum via LDS bf16 buffer (no per-step shfl);
// gate/u*D applied in a coalesced epilogue reading XZ/XC from global.
// PHASE 1: SP = exp(An*sum(dt)) [log-space product], SH = h_end.
// PHASE 3: h_init = in-block prefix over SP/SH; Y = (y + u*D)*silu(z).
template<int PHASE>
__global__ __launch_bounds__(256,4)
void scan_phase(const unsigned* __restrict__ DTW, const bf16* __restrict__ XC,
                const float* __restrict__ XD, const bf16* __restrict__ XZ,
                const bf16* __restrict__ Al, const bf16* __restrict__ Dp,
                float* __restrict__ SP, float* __restrict__ SH,
                bf16* __restrict__ Y){
    int dirb = blockIdx.z, dir = dirb >> 1, b = dirb & 1;
    int c    = blockIdx.y;
    int d0   = blockIdx.x*128;
    int tid  = threadIdx.x;
    int dl   = tid >> 1, nh = tid & 1;
    int d    = d0 + dl;
    int dcol = tid & 127;

    __shared__ unsigned sDTW[HC][128];                      // packed (dt, dt*u)
    __shared__ float    sBC[HC][32];                        // B[16] C[16]
    __shared__ bf16     sOutH[(PHASE==3) ? 2*HC*128 : 2];   // per-half y

    float An[8];
    {
        const bf16* ap = Al + ((size_t)dir*DI + d)*DS + nh*8;
        bf16x8 av = ld8(ap);
        #pragma unroll
        for (int j=0;j<8;++j) An[j] = -__expf((float)av[j]);
    }

    float h[8], S = 0.f;
    #pragma unroll
    for (int j=0;j<8;++j) h[j] = 0.f;
    size_t so = ((size_t)(dirb*NCH + c)*DI + d)*DS + nh*8;
    if (PHASE == 3){
        for (int cc=0; cc<c; ++cc){
            size_t o = ((size_t)(dirb*NCH + cc)*DI + d)*DS + nh*8;
            f32x4 p0 = *(const f32x4*)&SP[o];
            f32x4 p1 = *(const f32x4*)&SP[o+4];
            f32x4 h0 = *(const f32x4*)&SH[o];
            f32x4 h1 = *(const f32x4*)&SH[o+4];
            #pragma unroll
            for (int j=0;j<4;++j){
                h[j]   = p0[j]*h[j]   + h0[j];
                h[4+j] = p1[j]*h[4+j] + h1[j];
            }
        }
    }

    const unsigned* DTWb = DTW + ((size_t)dir*ROWS + b*L_ + c*CHUNK)*DI + d0;
    float Dv = (PHASE==3) ? b2f(Dp[dir*DI + d0 + dcol]) : 0.f;

    for (int hc=0; hc<2; ++hc){
        // stage packed dt/w: 2 rows of 128 per iter, coalesced
        {
            int t0 = tid >> 7;   // 0..1
            #pragma unroll
            for (int it=0; it<16; ++it){
                int t = it*2 + t0;
                sDTW[t][dcol] = DTWb[(size_t)(hc*HC + t)*DI + dcol];
            }
        }
        // stage B/C
        #pragma unroll
        for (int it=0; it<4; ++it){
            int idx = it*256 + tid;       // 0..1023 = 32t x 32j
            int t = idx >> 5, j = idx & 31;
            sBC[t][j] = XD[((size_t)(b*L_) + c*CHUNK + hc*HC + t)*128 + dir*64 + 32 + j];
        }
        __syncthreads();

        #pragma unroll 4
        for (int tl=0; tl<HC; ++tl){
            unsigned dw = sDTW[tl][dl];
            float dtv = unpk_lo(dw), wv = unpk_hi(dw);
            const float* Bp = &sBC[tl][nh*8];
            float y = 0.f;
            if (PHASE == 1) S += dtv;
            #pragma unroll
            for (int j=0;j<8;++j){
                float dA = __expf(dtv*An[j]);
                h[j] = dA*h[j] + wv*Bp[j];
                if (PHASE == 3) y += h[j]*Bp[16+j];
            }
            if (PHASE == 3)
                sOutH[(nh*HC + tl)*128 + dl] = __float2bfloat16(y);
        }

        if (PHASE == 3){
            __syncthreads();
            int t0 = tid >> 7;
            #pragma unroll
            for (int it=0; it<16; ++it){
                int t = it*2 + t0;        // 0..31
                int tg = c*CHUNK + hc*HC + t;
                size_t row = (size_t)b*L_ + tg;
                float y = b2f(sOutH[t*128 + dcol]) + b2f(sOutH[(HC + t)*128 + dcol]);
                size_t zrow = dir ? ((size_t)b*L_ + (L_-1-tg)) : row;
                float zv = b2f(XZ[zrow*4096 + dir*2048 + 1024 + d0 + dcol]);
                float g  = zv*(1.f/(1.f + __expf(-zv)));
                float u  = b2f(XC[((size_t)dir*ROWS + row)*DI + d0 + dcol]);
                Y[row*2048 + (size_t)dir*DI + d0 + dcol] =
                    __float2bfloat16(y*g + u*Dv*g);
            }
        }
        __syncthreads();
    }

    if (PHASE == 1){
        float pr[8];
        #pragma unroll
        for (int j=0;j<8;++j) pr[j] = __expf(An[j]*S);
        *(f32x4*)&SP[so]   = *(f32x4*)&pr[0];
        *(f32x4*)&SP[so+4] = *(f32x4*)&pr[4];
        *(f32x4*)&SH[so]   = *(f32x4*)&h[0];
        *(f32x4*)&SH[so+4] = *(f32x4*)&h[4];
    }
}

// ---------------------------------------------------------------- launch
extern "C" void kernel_launch(void* const* d_in, const int* in_sizes, int n_in,
                              void* d_out, int out_size, void* d_ws, size_t ws_size,
                              hipStream_t stream){
    const void* x_raw    = d_in[0];
    const void* inw_raw  = d_in[1];
    const void* convw_raw= d_in[2];
    const void* convb_raw= d_in[3];
    const void* xpw_raw  = d_in[4];
    const void* dtw_raw  = d_in[5];
    const void* dtb_raw  = d_in[6];
    const void* alog_raw = d_in[7];
    const void* dp_raw   = d_in[8];
    const void* outw_raw = d_in[9];
    const void* lnw_raw  = d_in[10];
    const void* lnb_raw  = d_in[11];
    const void* fnw_raw  = d_in[12];
    const void* fnb_raw  = d_in[13];

    char* ws = (char*)d_ws;
    float*    X   = (float*)   (ws + 0);          //  4 MB
    float*    R   = (float*)   (ws + 4194304);    //  4 MB
    bf16*     XN  = (bf16*)    (ws + 8388608);    //  2 MB
    bf16*     XZ  = (bf16*)    (ws + 10485760);   // 16 MB
    bf16*     XC  = (bf16*)    (ws + 27262976);   //  8 MB
    float*    XD  = (float*)   (ws + 35651584);   //  1 MB
    unsigned* DTW = (unsigned*)(ws + 36700160);   // 16 MB packed (dt, dt*u)
    bf16*     Y   = (bf16*)    (ws + 53477376);   //  8 MB
    float*    SP  = (float*)   (ws + 61865984);   //  4 MB
    float*    SH  = (float*)   (ws + 66060288);   //  4 MB
    bf16*     PP  = (bf16*)    (ws + 70254592);   //  2 MB
    bf16*     WIN = (bf16*)    (ws + 72351744);   // 16 MB
    bf16*     WOUT= (bf16*)    (ws + 89128960);   //  8 MB
    float*    PX  = (float*)   (ws + 97517568);   //  8 MB
    float*    PO  = (float*)   (ws + 105906176);  // 16 MB
    int*      FLAG= (int*)     (ws + 122683392);  //  4 B
    // total ~117 MB (ws = 256 MiB)

    detect_kernel<<<1,1,0,stream>>>(dp_raw, FLAG);
    {
        long total = (long)PO_END + N_WIN + N_WOUT + N_X;
        int blocks = (int)((total + 255)/256);
        megacvt_kernel<<<blocks,256,0,stream>>>(
            convw_raw, convb_raw, xpw_raw, dtw_raw, dtb_raw, alog_raw, dp_raw,
            lnw_raw, lnb_raw, fnw_raw, fnb_raw, inw_raw, outw_raw, x_raw,
            PP, WIN, WOUT, X, R, FLAG);
    }

    for (int l=0; l<4; ++l){
        ln_kernel<<<ROWS,64,0,stream>>>(l==0 ? X : PO, l==0 ? 1 : 4, R,
                                        PP+PO_LNW+l*DM, PP+PO_LNB+l*DM, XN, 0, FLAG);

        // in_proj: (2048x512) @ (4096x512)^T -> XZ bf16
        gemm_lds<2,2,1,bf16><<<dim3(32,16,1),256,0,stream>>>(
            XN, WIN + (size_t)l*2097152, XZ, 512, 512, 512, 4096, 1<<30, 0);

        conv_kernel<<<16384,256,0,stream>>>(XZ, PP+PO_CW + (size_t)l*2*DI*4,
                                            PP+PO_CB + l*2*DI, XC);

        // x_proj: dirs folded along M (XC is dir-major 4096x1024), N=64, split-K=8
        gemm_lds<2,1,8,float><<<dim3(1,32,8),128,0,stream>>>(
            XC, PP+PO_XPW + (size_t)l*2*64*DI, PX, 1024, 1024, 1024, 64,
            16, (long)64*DI);
        reduce_xd<<<1024,256,0,stream>>>(PX, XD);

        dtproj_kernel<<<16384,256,0,stream>>>(XD, PP+PO_DTW + (size_t)l*2*DI*DTR,
                                              PP+PO_DTB + l*2*DI, XC, DTW);

        scan_phase<1><<<dim3(DI/128,NCH,4),256,0,stream>>>(
            DTW, XC, XD, XZ, PP+PO_ALOG + (size_t)l*2*DI*DS, PP+PO_DP + l*2*DI,
            SP, SH, Y);
        scan_phase<3><<<dim3(DI/128,NCH,4),256,0,stream>>>(
            DTW, XC, XD, XZ, PP+PO_ALOG + (size_t)l*2*DI*DS, PP+PO_DP + l*2*DI,
            SP, SH, Y);

        // out_proj fused K=2048 (packed W), split-K=4 -> PO partials
        gemm_lds<2,2,4,float><<<dim3(4,16,4),256,0,stream>>>(
            Y, WOUT + (size_t)l*1048576, PO, 2048, 2048, 2048, 512, 1<<30, 0);
    }

    ln_kernel<<<ROWS,64,0,stream>>>(PO, 4, R, PP+PO_FNW, PP+PO_FNB, d_out, 1, FLAG);
}

// Round 9
// 771.178 us; speedup vs baseline: 1.0631x; 1.0631x over previous
//
#include <hip/hip_runtime.h>
#include <hip/hip_bf16.h>
#include <type_traits>

#define B_   2
#define L_   1024
#define DM   512
#define DI   1024
#define DS   16
#define DTR  32
#define ROWS (B_*L_)
#define NCH  32            // number of scan chunks
#define CHUNK (L_/NCH)     // 32 steps per chunk

// param-pool element offsets (bf16 pool holding all small/medium weights)
#define PO_CW    0
#define PO_CB    32768
#define PO_XPW   40960
#define PO_DTW   565248
#define PO_DTB   827392
#define PO_ALOG  835584
#define PO_DP    966656
#define PO_LNW   974848
#define PO_LNB   976896
#define PO_FNW   978944
#define PO_FNB   979456
#define PO_END   979968

#define N_WIN    (4*2097152)
#define N_WOUT   (4*1048576)
#define N_X      1048576

typedef __bf16 bf16x8 __attribute__((ext_vector_type(8)));
typedef float  f32x4  __attribute__((ext_vector_type(4)));
using bf16 = __hip_bfloat16;

__device__ __forceinline__ bf16x8 ld8(const bf16* p){
    return *reinterpret_cast<const bf16x8*>(p);
}
__device__ __forceinline__ float b2f(bf16 v){ return __bfloat162float(v); }

__device__ __forceinline__ unsigned pkbf2(float a, float b){
    bf16 ha = __float2bfloat16(a), hb = __float2bfloat16(b);
    unsigned short ua = *(unsigned short*)&ha, ub = *(unsigned short*)&hb;
    return (unsigned)ua | ((unsigned)ub << 16);
}
__device__ __forceinline__ float unpk_lo(unsigned v){
    unsigned x = v << 16; return __builtin_bit_cast(float, x);
}
__device__ __forceinline__ float unpk_hi(unsigned v){
    unsigned x = v & 0xffff0000u; return __builtin_bit_cast(float, x);
}

__device__ __forceinline__ void async_cp16(const void* g, void* s){
    __builtin_amdgcn_global_load_lds(
        (const __attribute__((address_space(1))) unsigned int*)g,
        (__attribute__((address_space(3))) unsigned int*)s, 16, 0, 0);
}

// ---------------------------------------------------------------- dtype detect
__global__ void detect_kernel(const void* Dp_raw, int* flag){
    *flag = (*(const unsigned int*)Dp_raw == 0x3F800000u) ? 1 : 0;
}

__device__ __forceinline__ bf16 cvload(const void* s, long o, int f){
    return f ? __float2bfloat16(((const float*)s)[o]) : ((const bf16*)s)[o];
}

// ---------------------------------------------------------------- mega convert
__global__ void megacvt_kernel(const void* cw, const void* cb, const void* xpw,
                               const void* dtw, const void* dtb, const void* al,
                               const void* dp, const void* lnw, const void* lnb,
                               const void* fnw, const void* fnb,
                               const void* inw, const void* outw, const void* xin,
                               bf16* PP, bf16* WIN, bf16* WOUT,
                               float* X, float* R, const int* flag){
    long i = (long)blockIdx.x*256 + threadIdx.x;
    int f = *flag;
    if (i < PO_END){
        const void* s; long o;
        if      (i < PO_CB)   { s = cw;  o = i; }
        else if (i < PO_XPW)  { s = cb;  o = i - PO_CB; }
        else if (i < PO_DTW)  { s = xpw; o = i - PO_XPW; }
        else if (i < PO_DTB)  { s = dtw; o = i - PO_DTW; }
        else if (i < PO_ALOG) { s = dtb; o = i - PO_DTB; }
        else if (i < PO_DP)   { s = al;  o = i - PO_ALOG; }
        else if (i < PO_LNW)  { s = dp;  o = i - PO_DP; }
        else if (i < PO_LNB)  { s = lnw; o = i - PO_LNW; }
        else if (i < PO_FNW)  { s = lnb; o = i - PO_LNB; }
        else if (i < PO_FNB)  { s = fnw; o = i - PO_FNW; }
        else                  { s = fnb; o = i - PO_FNB; }
        PP[i] = cvload(s, o, f);
        return;
    }
    i -= PO_END;
    if (i < N_WIN){ WIN[i] = cvload(inw, i, f); return; }
    i -= N_WIN;
    if (i < N_WOUT){
        long l = i >> 20, r = i & 1048575;
        long n = r >> 11, dir = (r >> 10) & 1, d = r & 1023;
        WOUT[i] = cvload(outw, ((l*2 + dir)*512 + n)*1024 + d, f);
        return;
    }
    i -= N_WOUT;
    if (i < N_X){
        X[i] = f ? ((const float*)xin)[i] : b2f(((const bf16*)xin)[i]);
        R[i] = 0.f;
    }
}

// ---------------------------------------------------------------- layernorm
__global__ void ln_kernel(const float* __restrict__ P, int nparts,
                          float* __restrict__ R,
                          const bf16* __restrict__ w, const bf16* __restrict__ b,
                          void* __restrict__ out, int mode, const int* flag){
    int row = blockIdx.x, lane = threadIdx.x;   // block = 64 (one wave)
    size_t base = (size_t)row*DM + lane*8;
    float v[8];
    *(float4*)&v[0] = *(const float4*)(P+base);
    *(float4*)&v[4] = *(const float4*)(P+base+4);
    for (int k=1; k<nparts; ++k){
        float4 a0 = *(const float4*)(P + (size_t)k*1048576 + base);
        float4 a1 = *(const float4*)(P + (size_t)k*1048576 + base + 4);
        v[0]+=a0.x; v[1]+=a0.y; v[2]+=a0.z; v[3]+=a0.w;
        v[4]+=a1.x; v[5]+=a1.y; v[6]+=a1.z; v[7]+=a1.w;
    }
    if (mode == 0){
        float4 r0 = *(const float4*)(R+base);
        float4 r1 = *(const float4*)(R+base+4);
        r0.x += v[0]; r0.y += v[1]; r0.z += v[2]; r0.w += v[3];
        r1.x += v[4]; r1.y += v[5]; r1.z += v[6]; r1.w += v[7];
        *(float4*)(R+base)   = r0;
        *(float4*)(R+base+4) = r1;
    } else {
        float4 r0 = *(const float4*)(R+base);
        float4 r1 = *(const float4*)(R+base+4);
        v[0]+=r0.x; v[1]+=r0.y; v[2]+=r0.z; v[3]+=r0.w;
        v[4]+=r1.x; v[5]+=r1.y; v[6]+=r1.z; v[7]+=r1.w;
    }
    float s=0.f, sq=0.f;
    #pragma unroll
    for (int j=0;j<8;++j){ s += v[j]; sq += v[j]*v[j]; }
    #pragma unroll
    for (int off=32; off>=1; off>>=1){
        s  += __shfl_xor(s,  off, 64);
        sq += __shfl_xor(sq, off, 64);
    }
    float mean = s*(1.f/DM);
    float var  = sq*(1.f/DM) - mean*mean;
    float rs   = rsqrtf(var + 1e-5f);
    bf16x8 wv = ld8(w + lane*8), bv = ld8(b + lane*8);
    float res[8];
    #pragma unroll
    for (int j=0;j<8;++j)
        res[j] = (v[j]-mean)*rs*(float)wv[j] + (float)bv[j];
    if (mode == 1 && *flag){
        float* of = (float*)out;
        *(float4*)(of+base)   = make_float4(res[0],res[1],res[2],res[3]);
        *(float4*)(of+base+4) = make_float4(res[4],res[5],res[6],res[7]);
    } else {
        union { bf16 h[8]; uint4 u; } o;
        #pragma unroll
        for (int j=0;j<8;++j) o.h[j] = __float2bfloat16(res[j]);
        *(uint4*)((bf16*)out + base) = o.u;
    }
}

// ---------------------------------------------------------------- LDS-staged GEMM
template<int WM, int WN, int SK, typename CT>
__global__ __launch_bounds__(WM*WN*64)
void gemm_lds(const bf16* __restrict__ A, const bf16* __restrict__ W,
              CT* __restrict__ C, int K, int lda, int ldw, int ldc,
              int selTiles, long wSel){
    constexpr int BM = WM*64, BN = WN*64, T = WM*WN*64;
    constexpr int RA = (BM*4)/T, RB = (BN*4)/T;
    __shared__ __align__(16) bf16 sA[BM*32];
    __shared__ __align__(16) bf16 sB[BN*32];
    int tid = threadIdx.x;
    int mtile = blockIdx.y, ntile = blockIdx.x;
    if (mtile >= selTiles) W += wSel;
    int m0 = mtile*BM, n0 = ntile*BN;
    int kPer = K/SK, kBeg = blockIdx.z*kPer, kEnd = kBeg + kPer;
    if (SK > 1)
        C += (size_t)blockIdx.z * (size_t)(gridDim.y*BM) * (size_t)(gridDim.x*BN);
    int wave = tid>>6, lane = tid&63, quad = lane>>4, r = lane&15;
    int wrow = wave / WN, wcol = wave % WN;
    const bf16* Abase = A + (size_t)m0*lda;
    const bf16* Wbase = W + (size_t)n0*ldw;
    f32x4 acc[4][4] = {};
    for (int k0 = kBeg; k0 < kEnd; k0 += 32){
        #pragma unroll
        for (int rr=0; rr<RA; ++rr){
            int q = rr*T + tid;
            async_cp16(Abase + (size_t)(q>>2)*lda + k0 + (q&3)*8, &sA[q*8]);
        }
        #pragma unroll
        for (int rr=0; rr<RB; ++rr){
            int q = rr*T + tid;
            async_cp16(Wbase + (size_t)(q>>2)*ldw + k0 + (q&3)*8, &sB[q*8]);
        }
        __syncthreads();
        bf16x8 af[4], bw[4];
        #pragma unroll
        for (int mt=0; mt<4; ++mt)
            af[mt] = *(const bf16x8*)&sA[(wrow*64 + mt*16 + r)*32 + quad*8];
        #pragma unroll
        for (int nt=0; nt<4; ++nt)
            bw[nt] = *(const bf16x8*)&sB[(wcol*64 + nt*16 + r)*32 + quad*8];
        #pragma unroll
        for (int mt=0; mt<4; ++mt)
            #pragma unroll
            for (int nt=0; nt<4; ++nt)
                acc[mt][nt] = __builtin_amdgcn_mfma_f32_16x16x32_bf16(
                    af[mt], bw[nt], acc[mt][nt], 0,0,0);
        __syncthreads();
    }
    #pragma unroll
    for (int mt=0; mt<4; ++mt){
        #pragma unroll
        for (int nt=0; nt<4; ++nt){
            int col = n0 + wcol*64 + nt*16 + r;
            #pragma unroll
            for (int ri=0; ri<4; ++ri){
                int row = m0 + wrow*64 + mt*16 + quad*4 + ri;
                size_t idx = (size_t)row*ldc + col;
                if constexpr (std::is_same<CT, bf16>::value)
                    C[idx] = __float2bfloat16(acc[mt][nt][ri]);
                else
                    C[idx] = acc[mt][nt][ri];
            }
        }
    }
}

// reduce 8 x_proj partials [8][4096*64] -> XD[row][dir*64+j]
__global__ void reduce_xd(const float* __restrict__ P, float* __restrict__ XD){
    int i = blockIdx.x*256 + threadIdx.x;    // 262144
    float s = 0.f;
    #pragma unroll
    for (int k=0;k<8;++k) s += P[k*262144 + i];
    int j = i & 63, grow = i >> 6, dir = grow >> 11, row = grow & 2047;
    XD[row*128 + dir*64 + j] = s;
}

// ---------------------------------------------------------------- causal depthwise conv (k=4) + silu + gate pack
// also emits GU = packed (silu(z), u*D*silu(z)) in scan layout
__global__ void conv_kernel(const bf16* __restrict__ XZ, const bf16* __restrict__ cw,
                            const bf16* __restrict__ cb, const bf16* __restrict__ Dp,
                            bf16* __restrict__ XC, unsigned* __restrict__ GU){
    int id  = blockIdx.x*256 + threadIdx.x;
    int d   = id & (DI-1);
    int t   = (id >> 10) & (L_-1);
    int b   = (id >> 20) & 1;
    int dir = id >> 21;
    float wv[4];
    #pragma unroll
    for (int k=0;k<4;++k) wv[k] = b2f(cw[((size_t)dir*DI + d)*4 + k]);
    float acc = b2f(cb[dir*DI + d]);
    #pragma unroll
    for (int k=0;k<4;++k){
        int tau = t - 3 + k;
        if (tau >= 0){
            int sig = dir ? (L_-1-tau) : tau;
            acc += wv[k] * b2f(XZ[((size_t)(b*L_ + sig))*4096 + dir*2048 + d]);
        }
    }
    float u = acc * (1.f/(1.f + __expf(-acc)));
    size_t idx = ((size_t)dir*ROWS + (size_t)b*L_ + t)*DI + d;
    XC[idx] = __float2bfloat16(u);
    // gate: z row is the dir-flipped row of output time t (== conv tap k=3 row)
    int sig3 = dir ? (L_-1-t) : t;
    float zv = b2f(XZ[((size_t)(b*L_ + sig3))*4096 + dir*2048 + 1024 + d]);
    float g  = zv*(1.f/(1.f + __expf(-zv)));
    float Dv = b2f(Dp[dir*DI + d]);
    GU[idx] = pkbf2(g, u*Dv*g);
}

// ---------------------------------------------------------------- dt projection + softplus + pack (dt, dt*u)
__global__ void dtproj_kernel(const float* __restrict__ XD, const bf16* __restrict__ dtw,
                              const bf16* __restrict__ dtb, const bf16* __restrict__ XC,
                              unsigned* __restrict__ DTW){
    int id  = blockIdx.x*256 + threadIdx.x;
    int d   = id & (DI-1);
    int row = (id >> 10) & (ROWS-1);
    int dir = id >> 21;
    const float* xr = XD + (size_t)row*128 + dir*64;
    const bf16*  wp = dtw + ((size_t)dir*DI + d)*DTR;
    float acc = b2f(dtb[dir*DI + d]);
    #pragma unroll
    for (int kk=0;kk<4;++kk){
        bf16x8 wv = ld8(wp + kk*8);
        #pragma unroll
        for (int j=0;j<8;++j) acc += xr[kk*8+j]*(float)wv[j];
    }
    float sp = acc > 20.f ? acc : log1pf(__expf(acc));
    size_t idx = ((size_t)dir*ROWS + row)*DI + d;
    float u = b2f(XC[idx]);
    DTW[idx] = pkbf2(sp, sp*u);
}

// ---------------------------------------------------------------- selective scan v6
// thread = (d, n-half): 8 states in registers; block = 128 d x 2 halves (256 thr)
// grid (8, NCH=32, 4dirb) = 1024 blocks -> 4 blocks/CU. Staging = pure
// global_load_lds DMA of precomputed packed DTW / GU / BC. Per-step: 1 LDS
// dword + 8 exp + FMAs; y cross-half via shfl (fp32); strided bf16 Y store.
// PHASE 1: SP = prod(dA), SH = h_end.
// PHASE 3: h_init = in-block prefix over SP/SH; Y = (y + u*D)*silu(z).
template<int PHASE>
__global__ __launch_bounds__(256)
void scan_phase(const unsigned* __restrict__ DTW, const unsigned* __restrict__ GU,
                const float* __restrict__ XD, const bf16* __restrict__ Al,
                float* __restrict__ SP, float* __restrict__ SH,
                bf16* __restrict__ Y){
    int dirb = blockIdx.z, dir = dirb >> 1, b = dirb & 1;
    int c    = blockIdx.y;
    int d0   = blockIdx.x*128;
    int tid  = threadIdx.x;
    int dl   = tid >> 1, nh = tid & 1;
    int d    = d0 + dl;

    __shared__ __align__(16) unsigned sDTW[CHUNK*128];              // packed (dt, dt*u)
    __shared__ __align__(16) float    sBC[CHUNK][32];               // B[16] C[16]
    __shared__ __align__(16) unsigned sGU[(PHASE==3)?CHUNK*128:4];  // packed (g, u*D*g)

    const unsigned* DTWb = DTW + ((size_t)dir*ROWS + b*L_ + c*CHUNK)*DI + d0;
    #pragma unroll
    for (int it=0; it<4; ++it){
        int q = it*256 + tid;          // 0..1023 = 32 rows x 32 x 16B
        int t = q >> 5, c4 = q & 31;
        async_cp16(DTWb + (size_t)t*DI + c4*4, &sDTW[q*4]);
    }
    if (PHASE == 3){
        const unsigned* GUb = GU + ((size_t)dir*ROWS + b*L_ + c*CHUNK)*DI + d0;
        #pragma unroll
        for (int it=0; it<4; ++it){
            int q = it*256 + tid;
            int t = q >> 5, c4 = q & 31;
            async_cp16(GUb + (size_t)t*DI + c4*4, &sGU[q*4]);
        }
    }
    {
        int t = tid >> 3, j = tid & 7;  // 32 rows x 8 x 16B
        async_cp16(XD + ((size_t)(b*L_) + c*CHUNK + t)*128 + dir*64 + 32 + j*4,
                   &sBC[t][j*4]);
    }

    float An[8];
    {
        const bf16* ap = Al + ((size_t)dir*DI + d)*DS + nh*8;
        bf16x8 av = ld8(ap);
        #pragma unroll
        for (int j=0;j<8;++j) An[j] = -__expf((float)av[j]);
    }

    float h[8], pr[8];
    #pragma unroll
    for (int j=0;j<8;++j){ h[j]=0.f; pr[j]=1.f; }
    size_t so = ((size_t)(dirb*NCH + c)*DI + d)*DS + nh*8;
    if (PHASE == 3){
        // h_init = prefix combine over chunks < c
        for (int cc=0; cc<c; ++cc){
            size_t o = ((size_t)(dirb*NCH + cc)*DI + d)*DS + nh*8;
            f32x4 p0 = *(const f32x4*)&SP[o];
            f32x4 p1 = *(const f32x4*)&SP[o+4];
            f32x4 h0 = *(const f32x4*)&SH[o];
            f32x4 h1 = *(const f32x4*)&SH[o+4];
            #pragma unroll
            for (int j=0;j<4;++j){
                h[j]   = p0[j]*h[j]   + h0[j];
                h[4+j] = p1[j]*h[4+j] + h1[j];
            }
        }
    }
    __syncthreads();

    bf16* Yp = Y + ((size_t)b*L_ + c*CHUNK)*2048 + dir*DI + d;

    #pragma unroll 4
    for (int tl=0; tl<CHUNK; ++tl){
        unsigned dw = sDTW[tl*128 + dl];
        float dtv = unpk_lo(dw), wv = unpk_hi(dw);
        const float* Bp = &sBC[tl][nh*8];
        float y = 0.f;
        #pragma unroll
        for (int j=0;j<8;++j){
            float dA = __expf(dtv*An[j]);
            h[j] = dA*h[j] + wv*Bp[j];
            if (PHASE == 1) pr[j] *= dA;
            else            y += h[j]*Bp[16+j];
        }
        if (PHASE == 3){
            y += __shfl_xor(y, 1, 64);    // add other n-half (lane pair)
            if (nh == 0){
                unsigned gu = sGU[tl*128 + dl];
                Yp[(size_t)tl*2048] = __float2bfloat16(y*unpk_lo(gu) + unpk_hi(gu));
            }
        }
    }
    if (PHASE == 1){
        *(f32x4*)&SP[so]   = *(f32x4*)&pr[0];
        *(f32x4*)&SP[so+4] = *(f32x4*)&pr[4];
        *(f32x4*)&SH[so]   = *(f32x4*)&h[0];
        *(f32x4*)&SH[so+4] = *(f32x4*)&h[4];
    }
}

// ---------------------------------------------------------------- launch
extern "C" void kernel_launch(void* const* d_in, const int* in_sizes, int n_in,
                              void* d_out, int out_size, void* d_ws, size_t ws_size,
                              hipStream_t stream){
    const void* x_raw    = d_in[0];
    const void* inw_raw  = d_in[1];
    const void* convw_raw= d_in[2];
    const void* convb_raw= d_in[3];
    const void* xpw_raw  = d_in[4];
    const void* dtw_raw  = d_in[5];
    const void* dtb_raw  = d_in[6];
    const void* alog_raw = d_in[7];
    const void* dp_raw   = d_in[8];
    const void* outw_raw = d_in[9];
    const void* lnw_raw  = d_in[10];
    const void* lnb_raw  = d_in[11];
    const void* fnw_raw  = d_in[12];
    const void* fnb_raw  = d_in[13];

    char* ws = (char*)d_ws;
    float*    X   = (float*)   (ws + 0);           //  4 MB
    float*    R   = (float*)   (ws + 4194304);     //  4 MB
    bf16*     XN  = (bf16*)    (ws + 8388608);     //  2 MB
    bf16*     XZ  = (bf16*)    (ws + 10485760);    // 16 MB
    bf16*     XC  = (bf16*)    (ws + 27262976);    //  8 MB
    float*    XD  = (float*)   (ws + 35651584);    //  1 MB
    unsigned* DTW = (unsigned*)(ws + 36700160);    // 16 MB packed (dt, dt*u)
    unsigned* GU  = (unsigned*)(ws + 52428800);    // 16 MB packed (g, u*D*g)
    bf16*     Y   = (bf16*)    (ws + 68157440);    //  8 MB
    float*    SP  = (float*)   (ws + 76546048);    //  8 MB
    float*    SH  = (float*)   (ws + 84934656);    //  8 MB
    bf16*     PP  = (bf16*)    (ws + 93323264);    //  2 MB
    bf16*     WIN = (bf16*)    (ws + 95420416);    // 16 MB
    bf16*     WOUT= (bf16*)    (ws + 112197632);   //  8 MB
    float*    PX  = (float*)   (ws + 120586240);   //  8 MB
    float*    PO  = (float*)   (ws + 128974848);   // 16 MB
    int*      FLAG= (int*)     (ws + 145752064);   //  4 B
    // total ~139 MB (ws = 256 MiB)

    detect_kernel<<<1,1,0,stream>>>(dp_raw, FLAG);
    {
        long total = (long)PO_END + N_WIN + N_WOUT + N_X;
        int blocks = (int)((total + 255)/256);
        megacvt_kernel<<<blocks,256,0,stream>>>(
            convw_raw, convb_raw, xpw_raw, dtw_raw, dtb_raw, alog_raw, dp_raw,
            lnw_raw, lnb_raw, fnw_raw, fnb_raw, inw_raw, outw_raw, x_raw,
            PP, WIN, WOUT, X, R, FLAG);
    }

    for (int l=0; l<4; ++l){
        ln_kernel<<<ROWS,64,0,stream>>>(l==0 ? X : PO, l==0 ? 1 : 4, R,
                                        PP+PO_LNW+l*DM, PP+PO_LNB+l*DM, XN, 0, FLAG);

        // in_proj: (2048x512) @ (4096x512)^T -> XZ bf16
        gemm_lds<2,2,1,bf16><<<dim3(32,16,1),256,0,stream>>>(
            XN, WIN + (size_t)l*2097152, XZ, 512, 512, 512, 4096, 1<<30, 0);

        conv_kernel<<<16384,256,0,stream>>>(XZ, PP+PO_CW + (size_t)l*2*DI*4,
                                            PP+PO_CB + l*2*DI, PP+PO_DP + l*2*DI,
                                            XC, GU);

        // x_proj: dirs folded along M (XC is dir-major 4096x1024), N=64, split-K=8
        gemm_lds<2,1,8,float><<<dim3(1,32,8),128,0,stream>>>(
            XC, PP+PO_XPW + (size_t)l*2*64*DI, PX, 1024, 1024, 1024, 64,
            16, (long)64*DI);
        reduce_xd<<<1024,256,0,stream>>>(PX, XD);

        dtproj_kernel<<<16384,256,0,stream>>>(XD, PP+PO_DTW + (size_t)l*2*DI*DTR,
                                              PP+PO_DTB + l*2*DI, XC, DTW);

        scan_phase<1><<<dim3(DI/128,NCH,4),256,0,stream>>>(
            DTW, GU, XD, PP+PO_ALOG + (size_t)l*2*DI*DS, SP, SH, Y);
        scan_phase<3><<<dim3(DI/128,NCH,4),256,0,stream>>>(
            DTW, GU, XD, PP+PO_ALOG + (size_t)l*2*DI*DS, SP, SH, Y);

        // out_proj fused K=2048 (packed W), split-K=4 -> PO partials
        gemm_lds<2,2,4,float><<<dim3(4,16,4),256,0,stream>>>(
            Y, WOUT + (size_t)l*1048576, PO, 2048, 2048, 2048, 512, 1<<30, 0);
    }

    ln_kernel<<<ROWS,64,0,stream>>>(PO, 4, R, PP+PO_FNW, PP+PO_FNB, d_out, 1, FLAG);
}

// Round 10
// 701.790 us; speedup vs baseline: 1.1682x; 1.0989x over previous
//
#include <hip/hip_runtime.h>
#include <hip/hip_bf16.h>
#include <type_traits>

#define B_   2
#define L_   1024
#define DM   512
#define DI   1024
#define DS   16
#define DTR  32
#define ROWS (B_*L_)
#define NCH  32            // number of scan chunks
#define CHUNK (L_/NCH)     // 32 steps per chunk

// param-pool element offsets (bf16 pool holding all small/medium weights)
#define PO_CW    0
#define PO_CB    32768
#define PO_XPW   40960
#define PO_DTW   565248
#define PO_DTB   827392
#define PO_ALOG  835584
#define PO_DP    966656
#define PO_LNW   974848
#define PO_LNB   976896
#define PO_FNW   978944
#define PO_FNB   979456
#define PO_END   979968

#define N_WIN    (4*2097152)
#define N_WOUT   (4*1048576)
#define N_X      1048576

typedef __bf16 bf16x8 __attribute__((ext_vector_type(8)));
typedef float  f32x4  __attribute__((ext_vector_type(4)));
using bf16 = __hip_bfloat16;

__device__ __forceinline__ bf16x8 ld8(const bf16* p){
    return *reinterpret_cast<const bf16x8*>(p);
}
__device__ __forceinline__ float b2f(bf16 v){ return __bfloat162float(v); }

__device__ __forceinline__ unsigned pkbf2(float a, float b){
    bf16 ha = __float2bfloat16(a), hb = __float2bfloat16(b);
    unsigned short ua = *(unsigned short*)&ha, ub = *(unsigned short*)&hb;
    return (unsigned)ua | ((unsigned)ub << 16);
}
__device__ __forceinline__ float unpk_lo(unsigned v){
    unsigned x = v << 16; return __builtin_bit_cast(float, x);
}
__device__ __forceinline__ float unpk_hi(unsigned v){
    unsigned x = v & 0xffff0000u; return __builtin_bit_cast(float, x);
}

__device__ __forceinline__ void async_cp16(const void* g, void* s){
    __builtin_amdgcn_global_load_lds(
        (const __attribute__((address_space(1))) unsigned int*)g,
        (__attribute__((address_space(3))) unsigned int*)s, 16, 0, 0);
}

// ---------------------------------------------------------------- dtype detect
__global__ void detect_kernel(const void* Dp_raw, int* flag){
    *flag = (*(const unsigned int*)Dp_raw == 0x3F800000u) ? 1 : 0;
}

__device__ __forceinline__ bf16 cvload(const void* s, long o, int f){
    return f ? __float2bfloat16(((const float*)s)[o]) : ((const bf16*)s)[o];
}

// ---------------------------------------------------------------- mega convert
__global__ void megacvt_kernel(const void* cw, const void* cb, const void* xpw,
                               const void* dtw, const void* dtb, const void* al,
                               const void* dp, const void* lnw, const void* lnb,
                               const void* fnw, const void* fnb,
                               const void* inw, const void* outw, const void* xin,
                               bf16* PP, bf16* WIN, bf16* WOUT,
                               float* X, float* R, const int* flag){
    long i = (long)blockIdx.x*256 + threadIdx.x;
    int f = *flag;
    if (i < PO_END){
        const void* s; long o;
        if      (i < PO_CB)   { s = cw;  o = i; }
        else if (i < PO_XPW)  { s = cb;  o = i - PO_CB; }
        else if (i < PO_DTW)  { s = xpw; o = i - PO_XPW; }
        else if (i < PO_DTB)  { s = dtw; o = i - PO_DTW; }
        else if (i < PO_ALOG) { s = dtb; o = i - PO_DTB; }
        else if (i < PO_DP)   { s = al;  o = i - PO_ALOG; }
        else if (i < PO_LNW)  { s = dp;  o = i - PO_DP; }
        else if (i < PO_LNB)  { s = lnw; o = i - PO_LNW; }
        else if (i < PO_FNW)  { s = lnb; o = i - PO_LNB; }
        else if (i < PO_FNB)  { s = fnw; o = i - PO_FNW; }
        else                  { s = fnb; o = i - PO_FNB; }
        PP[i] = cvload(s, o, f);
        return;
    }
    i -= PO_END;
    if (i < N_WIN){ WIN[i] = cvload(inw, i, f); return; }
    i -= N_WIN;
    if (i < N_WOUT){
        long l = i >> 20, r = i & 1048575;
        long n = r >> 11, dir = (r >> 10) & 1, d = r & 1023;
        WOUT[i] = cvload(outw, ((l*2 + dir)*512 + n)*1024 + d, f);
        return;
    }
    i -= N_WOUT;
    if (i < N_X){
        X[i] = f ? ((const float*)xin)[i] : b2f(((const bf16*)xin)[i]);
        R[i] = 0.f;
    }
}

// ---------------------------------------------------------------- layernorm
__global__ void ln_kernel(const float* __restrict__ P, int nparts,
                          float* __restrict__ R,
                          const bf16* __restrict__ w, const bf16* __restrict__ b,
                          void* __restrict__ out, int mode, const int* flag){
    int row = blockIdx.x, lane = threadIdx.x;   // block = 64 (one wave)
    size_t base = (size_t)row*DM + lane*8;
    float v[8];
    *(float4*)&v[0] = *(const float4*)(P+base);
    *(float4*)&v[4] = *(const float4*)(P+base+4);
    for (int k=1; k<nparts; ++k){
        float4 a0 = *(const float4*)(P + (size_t)k*1048576 + base);
        float4 a1 = *(const float4*)(P + (size_t)k*1048576 + base + 4);
        v[0]+=a0.x; v[1]+=a0.y; v[2]+=a0.z; v[3]+=a0.w;
        v[4]+=a1.x; v[5]+=a1.y; v[6]+=a1.z; v[7]+=a1.w;
    }
    if (mode == 0){
        float4 r0 = *(const float4*)(R+base);
        float4 r1 = *(const float4*)(R+base+4);
        r0.x += v[0]; r0.y += v[1]; r0.z += v[2]; r0.w += v[3];
        r1.x += v[4]; r1.y += v[5]; r1.z += v[6]; r1.w += v[7];
        *(float4*)(R+base)   = r0;
        *(float4*)(R+base+4) = r1;
    } else {
        float4 r0 = *(const float4*)(R+base);
        float4 r1 = *(const float4*)(R+base+4);
        v[0]+=r0.x; v[1]+=r0.y; v[2]+=r0.z; v[3]+=r0.w;
        v[4]+=r1.x; v[5]+=r1.y; v[6]+=r1.z; v[7]+=r1.w;
    }
    float s=0.f, sq=0.f;
    #pragma unroll
    for (int j=0;j<8;++j){ s += v[j]; sq += v[j]*v[j]; }
    #pragma unroll
    for (int off=32; off>=1; off>>=1){
        s  += __shfl_xor(s,  off, 64);
        sq += __shfl_xor(sq, off, 64);
    }
    float mean = s*(1.f/DM);
    float var  = sq*(1.f/DM) - mean*mean;
    float rs   = rsqrtf(var + 1e-5f);
    bf16x8 wv = ld8(w + lane*8), bv = ld8(b + lane*8);
    float res[8];
    #pragma unroll
    for (int j=0;j<8;++j)
        res[j] = (v[j]-mean)*rs*(float)wv[j] + (float)bv[j];
    if (mode == 1 && *flag){
        float* of = (float*)out;
        *(float4*)(of+base)   = make_float4(res[0],res[1],res[2],res[3]);
        *(float4*)(of+base+4) = make_float4(res[4],res[5],res[6],res[7]);
    } else {
        union { bf16 h[8]; uint4 u; } o;
        #pragma unroll
        for (int j=0;j<8;++j) o.h[j] = __float2bfloat16(res[j]);
        *(uint4*)((bf16*)out + base) = o.u;
    }
}

// ---------------------------------------------------------------- LDS-staged GEMM (BK templated)
template<int WM, int WN, int SK, int BK, typename CT>
__global__ __launch_bounds__(WM*WN*64)
void gemm_lds(const bf16* __restrict__ A, const bf16* __restrict__ W,
              CT* __restrict__ C, int K, int lda, int ldw, int ldc,
              int selTiles, long wSel){
    constexpr int BM = WM*64, BN = WN*64, T = WM*WN*64;
    constexpr int KC = BK/8;                    // 16B chunks per row
    constexpr int RA = (BM*KC)/T, RB = (BN*KC)/T;
    __shared__ __align__(16) bf16 sA[BM*BK];
    __shared__ __align__(16) bf16 sB[BN*BK];
    int tid = threadIdx.x;
    int mtile = blockIdx.y, ntile = blockIdx.x;
    if (mtile >= selTiles) W += wSel;
    int m0 = mtile*BM, n0 = ntile*BN;
    int kPer = K/SK, kBeg = blockIdx.z*kPer, kEnd = kBeg + kPer;
    if (SK > 1)
        C += (size_t)blockIdx.z * (size_t)(gridDim.y*BM) * (size_t)(gridDim.x*BN);
    int wave = tid>>6, lane = tid&63, quad = lane>>4, r = lane&15;
    int wrow = wave / WN, wcol = wave % WN;
    const bf16* Abase = A + (size_t)m0*lda;
    const bf16* Wbase = W + (size_t)n0*ldw;
    f32x4 acc[4][4] = {};
    for (int k0 = kBeg; k0 < kEnd; k0 += BK){
        #pragma unroll
        for (int rr=0; rr<RA; ++rr){
            int q = rr*T + tid;
            int row = q/KC, cp = q%KC;
            async_cp16(Abase + (size_t)row*lda + k0 + cp*8, &sA[q*8]);
        }
        #pragma unroll
        for (int rr=0; rr<RB; ++rr){
            int q = rr*T + tid;
            int row = q/KC, cp = q%KC;
            async_cp16(Wbase + (size_t)row*ldw + k0 + cp*8, &sB[q*8]);
        }
        __syncthreads();
        #pragma unroll
        for (int ko=0; ko<BK; ko+=32){
            bf16x8 af[4], bw[4];
            #pragma unroll
            for (int mt=0; mt<4; ++mt)
                af[mt] = *(const bf16x8*)&sA[(wrow*64 + mt*16 + r)*BK + ko + quad*8];
            #pragma unroll
            for (int nt=0; nt<4; ++nt)
                bw[nt] = *(const bf16x8*)&sB[(wcol*64 + nt*16 + r)*BK + ko + quad*8];
            #pragma unroll
            for (int mt=0; mt<4; ++mt)
                #pragma unroll
                for (int nt=0; nt<4; ++nt)
                    acc[mt][nt] = __builtin_amdgcn_mfma_f32_16x16x32_bf16(
                        af[mt], bw[nt], acc[mt][nt], 0,0,0);
        }
        __syncthreads();
    }
    #pragma unroll
    for (int mt=0; mt<4; ++mt){
        #pragma unroll
        for (int nt=0; nt<4; ++nt){
            int col = n0 + wcol*64 + nt*16 + r;
            #pragma unroll
            for (int ri=0; ri<4; ++ri){
                int row = m0 + wrow*64 + mt*16 + quad*4 + ri;
                size_t idx = (size_t)row*ldc + col;
                if constexpr (std::is_same<CT, bf16>::value)
                    C[idx] = __float2bfloat16(acc[mt][nt][ri]);
                else
                    C[idx] = acc[mt][nt][ri];
            }
        }
    }
}

// ---------------------------------------------------------------- causal depthwise conv (k=4) + silu + gate pack
// 2 d per thread; also emits GU = packed (silu(z), u*D*silu(z)) in scan layout
__global__ void conv_kernel(const bf16* __restrict__ XZ, const bf16* __restrict__ cw,
                            const bf16* __restrict__ cb, const bf16* __restrict__ Dp,
                            bf16* __restrict__ XC, unsigned* __restrict__ GU){
    int id  = blockIdx.x*256 + threadIdx.x;     // 2^21 threads
    int d   = (id & 511) * 2;
    int t   = (id >> 9) & (L_-1);
    int b   = (id >> 19) & 1;
    int dir = id >> 20;
    bf16x8 wv8 = ld8(cw + ((size_t)dir*DI + d)*4);       // taps for d (0..3) and d+1 (4..7)
    unsigned pcb = *(const unsigned*)&cb[dir*DI + d];
    float acc0 = unpk_lo(pcb), acc1 = unpk_hi(pcb);
    #pragma unroll
    for (int k=0;k<4;++k){
        int tau = t - 3 + k;
        if (tau >= 0){
            int sig = dir ? (L_-1-tau) : tau;
            unsigned pz = *(const unsigned*)&XZ[((size_t)(b*L_ + sig))*4096 + dir*2048 + d];
            acc0 += (float)wv8[k]   * unpk_lo(pz);
            acc1 += (float)wv8[4+k] * unpk_hi(pz);
        }
    }
    float u0 = acc0 * (1.f/(1.f + __expf(-acc0)));
    float u1 = acc1 * (1.f/(1.f + __expf(-acc1)));
    size_t idx = ((size_t)dir*ROWS + (size_t)b*L_ + t)*DI + d;
    *(unsigned*)&XC[idx] = pkbf2(u0, u1);
    int sig3 = dir ? (L_-1-t) : t;
    unsigned pzz = *(const unsigned*)&XZ[((size_t)(b*L_ + sig3))*4096 + dir*2048 + 1024 + d];
    float z0 = unpk_lo(pzz), z1 = unpk_hi(pzz);
    float g0 = z0*(1.f/(1.f + __expf(-z0)));
    float g1 = z1*(1.f/(1.f + __expf(-z1)));
    unsigned pdv = *(const unsigned*)&Dp[dir*DI + d];
    *(uint2*)&GU[idx] = make_uint2(pkbf2(g0, u0*unpk_lo(pdv)*g0),
                                   pkbf2(g1, u1*unpk_hi(pdv)*g1));
}

// ---------------------------------------------------------------- dt projection (fused x_proj reduce) + softplus + pack
// reads 8 split-K partials PX directly; block = 256 d of one (dir,row).
// d-block 0 also writes the reduced B/C into XD.
__global__ void dtproj_kernel(const float* __restrict__ PX, const bf16* __restrict__ dtw,
                              const bf16* __restrict__ dtb, const bf16* __restrict__ XC,
                              unsigned* __restrict__ DTW, float* __restrict__ XD){
    int id  = blockIdx.x*256 + threadIdx.x;
    int d   = id & (DI-1);
    int row = (id >> 10) & (ROWS-1);
    int dir = id >> 21;
    int tid = threadIdx.x;
    int grow = dir*2048 + row;
    __shared__ float sXR[32];
    if (tid < 32){
        float s = 0.f;
        #pragma unroll
        for (int k=0;k<8;++k) s += PX[(size_t)k*262144 + (size_t)grow*64 + tid];
        sXR[tid] = s;
    } else if (tid < 64 && ((id >> 8) & 3) == 0){
        int j = tid - 32;
        float s = 0.f;
        #pragma unroll
        for (int k=0;k<8;++k) s += PX[(size_t)k*262144 + (size_t)grow*64 + 32 + j];
        XD[(size_t)row*128 + dir*64 + 32 + j] = s;
    }
    __syncthreads();
    const bf16* wp = dtw + ((size_t)dir*DI + d)*DTR;
    float acc = b2f(dtb[dir*DI + d]);
    #pragma unroll
    for (int kk=0;kk<4;++kk){
        bf16x8 wv = ld8(wp + kk*8);
        #pragma unroll
        for (int j=0;j<8;++j) acc += sXR[kk*8+j]*(float)wv[j];
    }
    float sp = acc > 20.f ? acc : log1pf(__expf(acc));
    size_t idx = ((size_t)dir*ROWS + row)*DI + d;
    float u = b2f(XC[idx]);
    DTW[idx] = pkbf2(sp, sp*u);
}

// ---------------------------------------------------------------- selective scan v6.1
template<int PHASE>
__global__ __launch_bounds__(256)
void scan_phase(const unsigned* __restrict__ DTW, const unsigned* __restrict__ GU,
                const float* __restrict__ XD, const bf16* __restrict__ Al,
                float* __restrict__ SP, float* __restrict__ SH,
                bf16* __restrict__ Y){
    int dirb = blockIdx.z, dir = dirb >> 1, b = dirb & 1;
    int c    = blockIdx.y;
    int d0   = blockIdx.x*128;
    int tid  = threadIdx.x;
    int dl   = tid >> 1, nh = tid & 1;
    int d    = d0 + dl;

    __shared__ __align__(16) unsigned sDTW[CHUNK*128];              // packed (dt, dt*u)
    __shared__ __align__(16) float    sBC[CHUNK][32];               // B[16] C[16]
    __shared__ __align__(16) unsigned sGU[(PHASE==3)?CHUNK*128:4];  // packed (g, u*D*g)

    const unsigned* DTWb = DTW + ((size_t)dir*ROWS + b*L_ + c*CHUNK)*DI + d0;
    #pragma unroll
    for (int it=0; it<4; ++it){
        int q = it*256 + tid;          // 0..1023 = 32 rows x 32 x 16B
        int t = q >> 5, c4 = q & 31;
        async_cp16(DTWb + (size_t)t*DI + c4*4, &sDTW[q*4]);
    }
    if (PHASE == 3){
        const unsigned* GUb = GU + ((size_t)dir*ROWS + b*L_ + c*CHUNK)*DI + d0;
        #pragma unroll
        for (int it=0; it<4; ++it){
            int q = it*256 + tid;
            int t = q >> 5, c4 = q & 31;
            async_cp16(GUb + (size_t)t*DI + c4*4, &sGU[q*4]);
        }
    }
    {
        int t = tid >> 3, j = tid & 7;  // 32 rows x 8 x 16B
        async_cp16(XD + ((size_t)(b*L_) + c*CHUNK + t)*128 + dir*64 + 32 + j*4,
                   &sBC[t][j*4]);
    }

    float An[8];
    {
        const bf16* ap = Al + ((size_t)dir*DI + d)*DS + nh*8;
        bf16x8 av = ld8(ap);
        #pragma unroll
        for (int j=0;j<8;++j) An[j] = -__expf((float)av[j]);
    }

    float h[8], pr[8];
    #pragma unroll
    for (int j=0;j<8;++j){ h[j]=0.f; pr[j]=1.f; }
    size_t so = ((size_t)(dirb*NCH + c)*DI + d)*DS + nh*8;
    if (PHASE == 3){
        for (int cc=0; cc<c; ++cc){
            size_t o = ((size_t)(dirb*NCH + cc)*DI + d)*DS + nh*8;
            f32x4 p0 = *(const f32x4*)&SP[o];
            f32x4 p1 = *(const f32x4*)&SP[o+4];
            f32x4 h0 = *(const f32x4*)&SH[o];
            f32x4 h1 = *(const f32x4*)&SH[o+4];
            #pragma unroll
            for (int j=0;j<4;++j){
                h[j]   = p0[j]*h[j]   + h0[j];
                h[4+j] = p1[j]*h[4+j] + h1[j];
            }
        }
    }
    __syncthreads();

    bf16* Yp = Y + ((size_t)b*L_ + c*CHUNK)*2048 + dir*DI + d;

    #pragma unroll 4
    for (int tl=0; tl<CHUNK; ++tl){
        unsigned dw = sDTW[tl*128 + dl];
        float dtv = unpk_lo(dw), wv = unpk_hi(dw);
        f32x4 Bv0 = *(const f32x4*)&sBC[tl][nh*8];
        f32x4 Bv1 = *(const f32x4*)&sBC[tl][nh*8+4];
        f32x4 Cv0 = *(const f32x4*)&sBC[tl][16+nh*8];
        f32x4 Cv1 = *(const f32x4*)&sBC[tl][16+nh*8+4];
        float y = 0.f;
        #pragma unroll
        for (int j=0;j<4;++j){
            float dA0 = __expf(dtv*An[j]);
            float dA1 = __expf(dtv*An[4+j]);
            h[j]   = dA0*h[j]   + wv*Bv0[j];
            h[4+j] = dA1*h[4+j] + wv*Bv1[j];
            if (PHASE == 1){ pr[j] *= dA0; pr[4+j] *= dA1; }
            else { y += h[j]*Cv0[j]; y += h[4+j]*Cv1[j]; }
        }
        if (PHASE == 3){
            y += __shfl_xor(y, 1, 64);    // add other n-half (lane pair)
            if (nh == 0){
                unsigned gu = sGU[tl*128 + dl];
                Yp[(size_t)tl*2048] = __float2bfloat16(y*unpk_lo(gu) + unpk_hi(gu));
            }
        }
    }
    if (PHASE == 1){
        *(f32x4*)&SP[so]   = *(f32x4*)&pr[0];
        *(f32x4*)&SP[so+4] = *(f32x4*)&pr[4];
        *(f32x4*)&SH[so]   = *(f32x4*)&h[0];
        *(f32x4*)&SH[so+4] = *(f32x4*)&h[4];
    }
}

// ---------------------------------------------------------------- launch
extern "C" void kernel_launch(void* const* d_in, const int* in_sizes, int n_in,
                              void* d_out, int out_size, void* d_ws, size_t ws_size,
                              hipStream_t stream){
    const void* x_raw    = d_in[0];
    const void* inw_raw  = d_in[1];
    const void* convw_raw= d_in[2];
    const void* convb_raw= d_in[3];
    const void* xpw_raw  = d_in[4];
    const void* dtw_raw  = d_in[5];
    const void* dtb_raw  = d_in[6];
    const void* alog_raw = d_in[7];
    const void* dp_raw   = d_in[8];
    const void* outw_raw = d_in[9];
    const void* lnw_raw  = d_in[10];
    const void* lnb_raw  = d_in[11];
    const void* fnw_raw  = d_in[12];
    const void* fnb_raw  = d_in[13];

    char* ws = (char*)d_ws;
    float*    X   = (float*)   (ws + 0);           //  4 MB
    float*    R   = (float*)   (ws + 4194304);     //  4 MB
    bf16*     XN  = (bf16*)    (ws + 8388608);     //  2 MB
    bf16*     XZ  = (bf16*)    (ws + 10485760);    // 16 MB
    bf16*     XC  = (bf16*)    (ws + 27262976);    //  8 MB
    float*    XD  = (float*)   (ws + 35651584);    //  1 MB
    unsigned* DTW = (unsigned*)(ws + 36700160);    // 16 MB packed (dt, dt*u)
    unsigned* GU  = (unsigned*)(ws + 52428800);    // 16 MB packed (g, u*D*g)
    bf16*     Y   = (bf16*)    (ws + 68157440);    //  8 MB
    float*    SP  = (float*)   (ws + 76546048);    //  8 MB
    float*    SH  = (float*)   (ws + 84934656);    //  8 MB
    bf16*     PP  = (bf16*)    (ws + 93323264);    //  2 MB
    bf16*     WIN = (bf16*)    (ws + 95420416);    // 16 MB
    bf16*     WOUT= (bf16*)    (ws + 112197632);   //  8 MB
    float*    PX  = (float*)   (ws + 120586240);   //  8 MB
    float*    PO  = (float*)   (ws + 128974848);   // 16 MB
    int*      FLAG= (int*)     (ws + 145752064);   //  4 B
    // total ~139 MB (ws = 256 MiB)

    detect_kernel<<<1,1,0,stream>>>(dp_raw, FLAG);
    {
        long total = (long)PO_END + N_WIN + N_WOUT + N_X;
        int blocks = (int)((total + 255)/256);
        megacvt_kernel<<<blocks,256,0,stream>>>(
            convw_raw, convb_raw, xpw_raw, dtw_raw, dtb_raw, alog_raw, dp_raw,
            lnw_raw, lnb_raw, fnw_raw, fnb_raw, inw_raw, outw_raw, x_raw,
            PP, WIN, WOUT, X, R, FLAG);
    }

    for (int l=0; l<4; ++l){
        ln_kernel<<<ROWS,64,0,stream>>>(l==0 ? X : PO, l==0 ? 1 : 4, R,
                                        PP+PO_LNW+l*DM, PP+PO_LNB+l*DM, XN, 0, FLAG);

        // in_proj: (2048x512) @ (4096x512)^T -> XZ bf16
        gemm_lds<2,2,1,64,bf16><<<dim3(32,16,1),256,0,stream>>>(
            XN, WIN + (size_t)l*2097152, XZ, 512, 512, 512, 4096, 1<<30, 0);

        conv_kernel<<<8192,256,0,stream>>>(XZ, PP+PO_CW + (size_t)l*2*DI*4,
                                           PP+PO_CB + l*2*DI, PP+PO_DP + l*2*DI,
                                           XC, GU);

        // x_proj: dirs folded along M (XC is dir-major 4096x1024), N=64, split-K=8
        gemm_lds<2,1,8,64,float><<<dim3(1,32,8),128,0,stream>>>(
            XC, PP+PO_XPW + (size_t)l*2*64*DI, PX, 1024, 1024, 1024, 64,
            16, (long)64*DI);

        // dt proj (fused split-K reduce) + B/C reduce into XD
        dtproj_kernel<<<16384,256,0,stream>>>(PX, PP+PO_DTW + (size_t)l*2*DI*DTR,
                                              PP+PO_DTB + l*2*DI, XC, DTW, XD);

        scan_phase<1><<<dim3(DI/128,NCH,4),256,0,stream>>>(
            DTW, GU, XD, PP+PO_ALOG + (size_t)l*2*DI*DS, SP, SH, Y);
        scan_phase<3><<<dim3(DI/128,NCH,4),256,0,stream>>>(
            DTW, GU, XD, PP+PO_ALOG + (size_t)l*2*DI*DS, SP, SH, Y);

        // out_proj fused K=2048 (packed W), split-K=4 -> PO partials
        gemm_lds<2,2,4,64,float><<<dim3(4,16,4),256,0,stream>>>(
            Y, WOUT + (size_t)l*1048576, PO, 2048, 2048, 2048, 512, 1<<30, 0);
    }

    ln_kernel<<<ROWS,64,0,stream>>>(PO, 4, R, PP+PO_FNW, PP+PO_FNB, d_out, 1, FLAG);
}